// Round 4
// baseline (441.918 us; speedup 1.0000x reference)
//
#include <hip/hip_runtime.h>
#include <hip/hip_fp16.h>

// cosFormer linear attention, MI355X. L=S=2048, B=4, E=1024.
// Pipeline: f32->f16 convert; 3 proj GEMMs (fp16 MFMA, fp32 acc, epilogue folds
// bias/relu/sin-cos concat); LDS-tiled transposes to get K-dim contiguous;
// k_sum + z reductions (f32); kv GEMM; attn GEMM (epilogue * z) -> f32 out.
// R1: fused launches (15 -> 8 dispatches).
// R2: XCD-chunked bijective blockIdx swizzle in all GEMMs. FETCH 204->49 MB
//     (= ideal) but dur only 125->115us: latency-bound, not BW-bound.
// R3: 2-phase overlapped K-loop (T3-lite): double-buffered LDS (2x32KB),
//     STAGE(t+1) issued BEFORE compute(t), ONE __syncthreads per K-step.
//     The barrier's vmcnt(0) drain now waits on ~600-cycle-old loads (free)
//     instead of just-issued ones. No counted vmcnt -> no race surface.
//     LDS layout unchanged (fragment-blocked, bank-conflict counter = 0).
// R4: resubmission of R3 (previous round hit GPU-acquisition timeout).

typedef _Float16 f16;
typedef f16 f16x8 __attribute__((ext_vector_type(8)));
typedef f16 f16x4 __attribute__((ext_vector_type(4)));
typedef float f32x4 __attribute__((ext_vector_type(4)));

#define AS1 __attribute__((address_space(1)))
#define AS3 __attribute__((address_space(3)))

__device__ __forceinline__ void gload_lds16(const void* g, void* l) {
  // async global->LDS, 16B/lane; LDS dest = wave-uniform base + lane*16
  __builtin_amdgcn_global_load_lds((const AS1 void*)g, (AS3 void*)l, 16, 0, 0);
}

// XCD-chunked bijective swizzle (T1). Requires nwg % 8 == 0 (all our grids).
__device__ __forceinline__ void xcd_swz(int& bx, int& by, int& bz) {
  const int nx = gridDim.x, ny = gridDim.y;
  const int p = blockIdx.x + nx * (blockIdx.y + ny * blockIdx.z);
  const int chunk = (nx * ny * gridDim.z) >> 3;
  const int l = (p & 7) * chunk + (p >> 3);
  bx = l % nx;
  by = (l / nx) % ny;
  bz = l / (nx * ny);
}

// ---------------------------------------------------------------------------
// f32 -> f16 convert (vectorized x4); z selects one of three src/dst pairs
__global__ void cvt3(const float* __restrict__ s0, const float* __restrict__ s1,
                     const float* __restrict__ s2, f16* __restrict__ d0,
                     f16* __restrict__ d1, f16* __restrict__ d2, int n4) {
  const int z = blockIdx.z;
  const float* s = (z == 0) ? s0 : (z == 1) ? s1 : s2;
  f16* d = (z == 0) ? d0 : (z == 1) ? d1 : d2;
  const int i = blockIdx.x * 256 + threadIdx.x;
  if (i >= n4) return;
  const float4 v = ((const float4*)s)[i];
  f16x4 o = { (f16)v.x, (f16)v.y, (f16)v.z, (f16)v.w };
  ((f16x4*)d)[i] = o;
}

// ---------------------------------------------------------------------------
// 2-phase double-buffered 128x128x(BK=64) fp16 MFMA loop:
//   acc[m][n] += sum_k A[m][k] * B[n][k]   (both operands k-contiguous)
// LDS: per buffer, 16 fragment-blocks of 1KB per matrix; block(mt,kt) filled so
// lane l's 16B = row (mt*16 + (l&15)), k (kt*32 + (l>>4)*8..+7) -> fragment
// ds_read_b128 at blockbase + lane*16 is conflict-free (counter-verified 0).
// Schedule per K-step: STAGE(t+1 -> buf^1) ; compute(t, buf) ; syncthreads.
// ds_reads of buf cannot hoist above the LDS-writing gloads (alias conservatism)
// so issue order is pinned without asm; the sync's vmcnt(0) drain is hidden
// under the compute phase.
__device__ __forceinline__ void mm_core(const f16* __restrict__ A, int lda,
                                        const f16* __restrict__ B, int ldb,
                                        int K, int m0, int n0,
                                        f16* As, f16* Bs, f32x4 (&acc)[4][4]) {
  const int tid  = threadIdx.x;
  const int lane = tid & 63;
  const int w    = tid >> 6;        // wave 0..3
  const int wm   = w >> 1, wn = w & 1;
  const int l15  = lane & 15;
  const int quad = lane >> 4;

  // staging pointers: wave w stages fragment-blocks bid = w*4 .. w*4+3 of A and B
  const f16* ag[4];
  const f16* bg[4];
  f16* al[4];
  f16* bl[4];
#pragma unroll
  for (int i = 0; i < 4; ++i) {
    const int bid = w * 4 + i;
    const int mt = bid >> 1;
    const int kt = bid & 1;
    ag[i] = A + (long)(m0 + mt * 16 + l15) * lda + kt * 32 + quad * 8;
    bg[i] = B + (long)(n0 + mt * 16 + l15) * ldb + kt * 32 + quad * 8;
    al[i] = As + bid * 512;         // buffer 0; buffer 1 at +8192 f16 (16KB)
    bl[i] = Bs + bid * 512;
  }

  // prologue: stage tile 0 into buffer 0
#pragma unroll
  for (int i = 0; i < 4; ++i) {
    gload_lds16(ag[i], al[i]);
    gload_lds16(bg[i], bl[i]);
  }
#pragma unroll
  for (int i = 0; i < 4; ++i) { ag[i] += 64; bg[i] += 64; }
  __syncthreads();                  // tile 0 resident

  const int nt = K >> 6;
  int cur = 0;
  for (int t = 0; t < nt; ++t) {
    // phase 1: issue next tile's loads into the other buffer (overlaps compute)
    if (t + 1 < nt) {
      const int nb = (cur ^ 1) * 8192;
#pragma unroll
      for (int i = 0; i < 4; ++i) {
        gload_lds16(ag[i], al[i] + nb);
        gload_lds16(bg[i], bl[i] + nb);
      }
#pragma unroll
      for (int i = 0; i < 4; ++i) { ag[i] += 64; bg[i] += 64; }
    }
    // phase 2: compute current buffer
    const f16* Ab = As + cur * 8192;
    const f16* Bb = Bs + cur * 8192;
#pragma unroll
    for (int kt = 0; kt < 2; ++kt) {
      f16x8 af[4], bf[4];
#pragma unroll
      for (int i = 0; i < 4; ++i)
        af[i] = *(const f16x8*)(Ab + ((wm * 4 + i) * 2 + kt) * 512 + lane * 8);
#pragma unroll
      for (int j = 0; j < 4; ++j)
        bf[j] = *(const f16x8*)(Bb + ((wn * 4 + j) * 2 + kt) * 512 + lane * 8);
#pragma unroll
      for (int i = 0; i < 4; ++i)
#pragma unroll
        for (int j = 0; j < 4; ++j)
          acc[i][j] = __builtin_amdgcn_mfma_f32_16x16x32_f16(af[i], bf[j], acc[i][j], 0, 0, 0);
    }
    __syncthreads();   // drains vmcnt (next tile ready) + read-write fence
    cur ^= 1;
  }
}

// ---------------------------------------------------------------------------
// Fused Q/K/V projection GEMM. grid = (8, 64, 3); z selects {A,W,bias,C,mode}.
// z=0: Q -> Qf (relu+bias, sin/cos dual write, ldc=2048)
// z=1: K -> Kn (same)
// z=2: V -> Vp (bias only, ldc=1024)
__launch_bounds__(256)
__global__ void proj_gemm(const f16* __restrict__ q16, const f16* __restrict__ k16,
                          const f16* __restrict__ v16, const f16* __restrict__ wq,
                          const f16* __restrict__ wk, const f16* __restrict__ wv,
                          const float* __restrict__ bq, const float* __restrict__ bk,
                          const float* __restrict__ bv,
                          f16* __restrict__ Qf, f16* __restrict__ Kn, f16* __restrict__ Vp) {
  __shared__ f16 As[2 * 16 * 512];   // 32 KB (double-buffered)
  __shared__ f16 Bs[2 * 16 * 512];   // 32 KB
  int bx, by, z;
  xcd_swz(bx, by, z);
  const f16* A = (z == 0) ? q16 : (z == 1) ? k16 : v16;
  const f16* B = (z == 0) ? wq : (z == 1) ? wk : wv;
  const float* bias = (z == 0) ? bq : (z == 1) ? bk : bv;
  const int m0 = by * 128;
  const int n0 = bx * 128;

  f32x4 acc[4][4] = {};
  mm_core(A, 1024, B, 1024, 1024, m0, n0, As, Bs, acc);

  const int tid  = threadIdx.x;
  const int lane = tid & 63;
  const int w    = tid >> 6;
  const int wm   = w >> 1, wn = w & 1;
  const int l15  = lane & 15;
  const int quad = lane >> 4;

  // C/D layout (verified m89/m91): col = lane&15, row = quad*4 + reg.
  if (z < 2) {
    f16* C = (z == 0) ? Qf : Kn;
    const int ldc = 2048, halfw = 1024;
#pragma unroll
    for (int i = 0; i < 4; ++i) {
      const int mg = m0 + wm * 64 + i * 16 + quad * 4;
      float sn[4], cn[4];
#pragma unroll
      for (int rr = 0; rr < 4; ++rr) {
        const int l = (mg + rr) >> 2;          // natural row = l*4 + b
        const float ang = 7.6699039394282066e-4f * (float)(l + 1);  // (pi/2)/2048 * (l+1)
        __sincosf(ang, &sn[rr], &cn[rr]);
      }
#pragma unroll
      for (int j = 0; j < 4; ++j) {
        const int ng = n0 + wn * 64 + j * 16 + l15;
        const float bc = bias[ng];
#pragma unroll
        for (int rr = 0; rr < 4; ++rr) {
          const float v = fmaxf(acc[i][j][rr] + bc, 0.f);
          C[(long)(mg + rr) * ldc + ng]         = (f16)(v * sn[rr]);
          C[(long)(mg + rr) * ldc + ng + halfw] = (f16)(v * cn[rr]);
        }
      }
    }
  } else {
    f16* C = Vp;
    const int ldc = 1024;
#pragma unroll
    for (int i = 0; i < 4; ++i) {
      const int mg = m0 + wm * 64 + i * 16 + quad * 4;
#pragma unroll
      for (int j = 0; j < 4; ++j) {
        const int ng = n0 + wn * 64 + j * 16 + l15;
        const float bc = bias[ng];
#pragma unroll
        for (int rr = 0; rr < 4; ++rr)
          C[(long)(mg + rr) * ldc + ng] = (f16)(acc[i][j][rr] + bc);
      }
    }
  }
}

// ---------------------------------------------------------------------------
// Generic GEMM (kv and attn stages).
// MODE 2: kv   -> f16 C = acc
// MODE 3: attn -> f32 C = acc * z[l*4+bz]
template<int MODE>
__launch_bounds__(256)
__global__ void gemm_bt(const f16* __restrict__ A, int lda,
                        const f16* __restrict__ B, int ldb,
                        void* __restrict__ Cout, int K, int ldc,
                        const float* __restrict__ zvec,
                        long abatch, long bbatch, long cbatch)
{
  __shared__ f16 As[2 * 16 * 512];   // 32 KB (double-buffered)
  __shared__ f16 Bs[2 * 16 * 512];   // 32 KB
  int bx, by, bz;
  xcd_swz(bx, by, bz);
  A += (long)bz * abatch;
  B += (long)bz * bbatch;
  const int m0 = by * 128;
  const int n0 = bx * 128;

  f32x4 acc[4][4] = {};
  mm_core(A, lda, B, ldb, K, m0, n0, As, Bs, acc);

  const int tid  = threadIdx.x;
  const int lane = tid & 63;
  const int w    = tid >> 6;
  const int wm   = w >> 1, wn = w & 1;
  const int l15  = lane & 15;
  const int quad = lane >> 4;

  if constexpr (MODE == 2) {
    f16* C = (f16*)Cout + (long)bz * cbatch;
#pragma unroll
    for (int i = 0; i < 4; ++i) {
      const int mg = m0 + wm * 64 + i * 16 + quad * 4;
#pragma unroll
      for (int j = 0; j < 4; ++j) {
        const int ng = n0 + wn * 64 + j * 16 + l15;
#pragma unroll
        for (int rr = 0; rr < 4; ++rr)
          C[(long)(mg + rr) * ldc + ng] = (f16)acc[i][j][rr];
      }
    }
  } else {  // MODE 3: attn, f32 out, scale by z
    float* C = (float*)Cout + (long)bz * cbatch;
#pragma unroll
    for (int i = 0; i < 4; ++i) {
      const int mg = m0 + wm * 64 + i * 16 + quad * 4;
      float zr[4];
#pragma unroll
      for (int rr = 0; rr < 4; ++rr) zr[rr] = zvec[(long)(mg + rr) * 4 + bz];
#pragma unroll
      for (int j = 0; j < 4; ++j) {
        const int ng = n0 + wn * 64 + j * 16 + l15;
#pragma unroll
        for (int rr = 0; rr < 4; ++rr)
          C[(long)(mg + rr) * ldc + ng] = acc[i][j][rr] * zr[rr];
      }
    }
  }
}

// ---------------------------------------------------------------------------
// fp16 64x64 LDS-tiled transpose, K and V fused in one launch.
// grid = (32, 32, 8): z<4 -> K batch z; z>=4 -> V batch z-4 (x<16 only).
__global__ void transpose_fused(const f16* __restrict__ Kn, f16* __restrict__ Kt,
                                const f16* __restrict__ Vp, f16* __restrict__ Vt) {
  __shared__ f16 tile[64 * 72];   // +8 halves pad (144B stride keeps 16B alignment)
  const int z = blockIdx.z;
  const f16* in;
  f16* out;
  long in_batch, out_batch;
  int ldin, ldout, b;
  if (z < 4) {
    in = Kn; out = Kt; in_batch = 2048; out_batch = 2048L * 2048;
    ldin = 8192; ldout = 2048; b = z;
  } else {
    if (blockIdx.x >= 16) return;   // V col dim is 1024 (uniform exit, pre-barrier)
    in = Vp; out = Vt; in_batch = 1024; out_batch = 1024L * 2048;
    ldin = 4096; ldout = 2048; b = z - 4;
  }
  in  += (long)b * in_batch;
  out += (long)b * out_batch;
  const int r0 = blockIdx.y * 64;
  const int c0 = blockIdx.x * 64;
  const int t  = threadIdx.x;
  {
    const int r = t >> 2, cs = (t & 3) * 16;
    const f16* src = in + (long)(r0 + r) * ldin + c0 + cs;
    f16x8 v0 = *(const f16x8*)(src);
    f16x8 v1 = *(const f16x8*)(src + 8);
    *(f16x8*)(tile + r * 72 + cs)     = v0;
    *(f16x8*)(tile + r * 72 + cs + 8) = v1;
  }
  __syncthreads();
  {
    const int c = t >> 2, rs = (t & 3) * 16;
    alignas(16) f16 tmp[16];
#pragma unroll
    for (int j = 0; j < 16; ++j) tmp[j] = tile[(rs + j) * 72 + c];
    f16* dst = out + (long)(c0 + c) * ldout + r0 + rs;
    *(f16x8*)(dst)     = *(const f16x8*)(tmp);
    *(f16x8*)(dst + 8) = *(const f16x8*)(tmp + 8);
  }
}

// ---------------------------------------------------------------------------
// k_sum[b][d] = sum_s K_t[b][d][s]  (one block per row of 2048)
__global__ void ksum_kernel(const f16* __restrict__ Kt, float* __restrict__ ks) {
  const long row = blockIdx.x;
  const int t = threadIdx.x;
  f16x8 v = *(const f16x8*)(Kt + row * 2048 + t * 8);
  float s = 0.f;
#pragma unroll
  for (int j = 0; j < 8; ++j) s += (float)v[j];
#pragma unroll
  for (int off = 32; off > 0; off >>= 1) s += __shfl_down(s, off, 64);
  __shared__ float red[4];
  if ((t & 63) == 0) red[t >> 6] = s;
  __syncthreads();
  if (t == 0) ks[row] = red[0] + red[1] + red[2] + red[3];
}

// z[r=l*4+b] = 1 / max(sum_d Q_[r][d] * k_sum[b][d], eps)
__global__ void z_kernel(const f16* __restrict__ Qf, const float* __restrict__ ks,
                         float* __restrict__ zb) {
  const long r = blockIdx.x;
  const int t = threadIdx.x;
  const int b = (int)(r & 3);
  f16x8 q = *(const f16x8*)(Qf + r * 2048 + t * 8);
  const float* kp = ks + b * 2048 + t * 8;
  float s = 0.f;
#pragma unroll
  for (int j = 0; j < 8; ++j) s += (float)q[j] * kp[j];
#pragma unroll
  for (int off = 32; off > 0; off >>= 1) s += __shfl_down(s, off, 64);
  __shared__ float red[4];
  if ((t & 63) == 0) red[t >> 6] = s;
  __syncthreads();
  if (t == 0) zb[r] = 1.f / fmaxf(red[0] + red[1] + red[2] + red[3], 1e-6f);
}

// ---------------------------------------------------------------------------
extern "C" void kernel_launch(void* const* d_in, const int* in_sizes, int n_in,
                              void* d_out, int out_size, void* d_ws, size_t ws_size,
                              hipStream_t stream) {
  const float* query = (const float*)d_in[0];
  const float* key_  = (const float*)d_in[1];
  const float* value = (const float*)d_in[2];
  const float* Wq    = (const float*)d_in[3];
  const float* bq    = (const float*)d_in[4];
  const float* Wk    = (const float*)d_in[5];
  const float* bk    = (const float*)d_in[6];
  const float* Wv    = (const float*)d_in[7];
  const float* bv    = (const float*)d_in[8];

  char* ws = (char*)d_ws;
  const size_t MB = 1ull << 20;
  // Workspace layout (peak 134 MB, with lifetime-based aliasing):
  f16* wq16 = (f16*)(ws + 0 * MB);    // 2 MB
  f16* wk16 = (f16*)(ws + 2 * MB);    // 2 MB
  f16* wv16 = (f16*)(ws + 4 * MB);    // 2 MB
  f16* q16  = (f16*)(ws + 6 * MB);    // 16 MB (dead after proj GEMMs)
  f16* k16  = (f16*)(ws + 22 * MB);   // 16 MB (dead after proj GEMMs)
  f16* v16  = (f16*)(ws + 38 * MB);   // 16 MB (dead after proj GEMMs)
  f16* Qf   = (f16*)(ws + 54 * MB);   // 32 MB  Q_ [l*4+b][2048]
  f16* Kn   = (f16*)(ws + 86 * MB);   // 32 MB  K_ natural [s*4+b][2048] (dead after transpose)
  f16* Vp   = (f16*)(ws + 118 * MB);  // 16 MB  V  natural [s*4+b][1024] (dead after transpose)
  f16* Kt   = (f16*)(ws + 6 * MB);    // 32 MB  K_t [b][d][s]   (aliases q16+k16)
  f16* Vt   = (f16*)(ws + 38 * MB);   // 16 MB  V_t [b][m][s]   (aliases v16)
  f16* kvb  = (f16*)(ws + 86 * MB);   // 16 MB  kv  [b][m][d]   (aliases Kn)
  float* ks = (float*)(ws + 102 * MB);  // 32 KB k_sum[b][d]
  float* zb = (float*)(ws + 103 * MB);  // 32 KB z[l*4+b]

  // 1) f32 -> f16 (2 fused launches)
  cvt3<<<dim3(8192, 1, 3), 256, 0, stream>>>(query, key_, value, q16, k16, v16, 2097152);
  cvt3<<<dim3(1024, 1, 3), 256, 0, stream>>>(Wq, Wk, Wv, wq16, wk16, wv16, 262144);

  // 2) projections fused (M=8192, N=1024, K=1024; z selects Q/K/V)
  proj_gemm<<<dim3(8, 64, 3), 256, 0, stream>>>(q16, k16, v16, wq16, wk16, wv16,
                                                bq, bk, bv, Qf, Kn, Vp);

  // 3) transposes fused: K_ [s][d] -> K_t [d][s]; V [s][m] -> V_t [m][s]
  transpose_fused<<<dim3(32, 32, 8), 256, 0, stream>>>(Kn, Kt, Vp, Vt);

  // 4) k_sum and z
  ksum_kernel<<<8192, 256, 0, stream>>>(Kt, ks);
  z_kernel<<<8192, 256, 0, stream>>>(Qf, ks, zb);

  // 5) kv[b][m][d] = sum_s V_t[m][s] * K_t[d][s]   (M=1024, N=2048, K=2048)
  gemm_bt<2><<<dim3(16, 8, 4), 256, 0, stream>>>(Vt, 2048, Kt, 2048, kvb, 2048, 2048,
                                                 nullptr, 1024L * 2048, 2048L * 2048, 1024L * 2048);
  // 6) attn[l][b][m] = z * sum_d Q_[l][d] * kv[m][d]  (M=2048, N=1024, K=2048), f32 out
  gemm_bt<3><<<dim3(8, 16, 4), 256, 0, stream>>>(Qf, 8192, kvb, 2048, d_out, 2048, 4096,
                                                 zb, 2048, 1024L * 2048, 1024);
}

// Round 6
// 420.358 us; speedup vs baseline: 1.0513x; 1.0513x over previous
//
#include <hip/hip_runtime.h>
#include <hip/hip_fp16.h>

// cosFormer linear attention, MI355X. L=S=2048, B=4, E=1024.
// Pipeline: f32->f16 convert; 3 proj GEMMs (fp16 MFMA, fp32 acc, epilogue folds
// bias/relu/sin-cos concat); LDS-tiled transposes to get K-dim contiguous;
// k_sum + z reductions (f32); kv GEMM; attn GEMM (epilogue * z) -> f32 out.
// R1: fused launches (15 -> 8 dispatches).
// R2: XCD-chunked bijective blockIdx swizzle in all GEMMs. FETCH 204->49 MB
//     (= ideal) but dur only 125->115us: latency-bound, not BW-bound.
// R3: 2-phase dbuf with RUNTIME buffer offsets -> REGRESSED 115->143us.
//     Diagnosis: compiler can't disambiguate gload_lds writes(buf^1) from
//     ds_reads(buf) within one LDS object -> conservative s_waitcnt vmcnt(0)
//     BEFORE the ds_reads -> load latency moved IN FRONT of compute.
// R5: STATIC double-buffer: 4 separate __shared__ arrays (As0/As1/Bs0/Bs1),
//     K-loop unrolled x2 so every stage/compute names a distinct array at
//     compile time. AA now proves write(As1) is disjoint from read(As0) -> no
//     vmcnt wait before ds_reads; the only vmcnt(0) drain is inside
//     __syncthreads() AFTER the MFMAs (hidden under ~600cy compute).
//     All K in {1024,2048} -> step count even, x2 unroll exact.
// R6: resubmission of R5 (previous round hit GPU-acquisition timeout).

typedef _Float16 f16;
typedef f16 f16x8 __attribute__((ext_vector_type(8)));
typedef f16 f16x4 __attribute__((ext_vector_type(4)));
typedef float f32x4 __attribute__((ext_vector_type(4)));

#define AS1 __attribute__((address_space(1)))
#define AS3 __attribute__((address_space(3)))

__device__ __forceinline__ void gload_lds16(const void* g, void* l) {
  // async global->LDS, 16B/lane; LDS dest = wave-uniform base + lane*16
  __builtin_amdgcn_global_load_lds((const AS1 void*)g, (AS3 void*)l, 16, 0, 0);
}

// XCD-chunked bijective swizzle (T1). Requires nwg % 8 == 0 (all our grids).
__device__ __forceinline__ void xcd_swz(int& bx, int& by, int& bz) {
  const int nx = gridDim.x, ny = gridDim.y;
  const int p = blockIdx.x + nx * (blockIdx.y + ny * blockIdx.z);
  const int chunk = (nx * ny * gridDim.z) >> 3;
  const int l = (p & 7) * chunk + (p >> 3);
  bx = l % nx;
  by = (l / nx) % ny;
  bz = l / (nx * ny);
}

// ---------------------------------------------------------------------------
// f32 -> f16 convert (vectorized x4); z selects one of three src/dst pairs
__global__ void cvt3(const float* __restrict__ s0, const float* __restrict__ s1,
                     const float* __restrict__ s2, f16* __restrict__ d0,
                     f16* __restrict__ d1, f16* __restrict__ d2, int n4) {
  const int z = blockIdx.z;
  const float* s = (z == 0) ? s0 : (z == 1) ? s1 : s2;
  f16* d = (z == 0) ? d0 : (z == 1) ? d1 : d2;
  const int i = blockIdx.x * 256 + threadIdx.x;
  if (i >= n4) return;
  const float4 v = ((const float4*)s)[i];
  f16x4 o = { (f16)v.x, (f16)v.y, (f16)v.z, (f16)v.w };
  ((f16x4*)d)[i] = o;
}

// ---------------------------------------------------------------------------
// Statically double-buffered 128x128x(BK=64) fp16 MFMA loop:
//   acc[m][n] += sum_k A[m][k] * B[n][k]   (both operands k-contiguous)
// LDS per buffer: 16 fragment-blocks of 1KB per matrix; block(mt,kt) filled so
// lane l's 16B = row (mt*16 + (l&15)), k (kt*32 + (l>>4)*8..+7) -> fragment
// ds_read_b128 at blockbase + lane*16 is conflict-free (counter-verified 0).
// Per phase: STAGE(next -> other buffer, statically named) ; COMPUTE(this
// buffer) ; __syncthreads.  Distinct __shared__ arrays let AA skip the
// conservative vmcnt wait before the ds_reads (the R3 failure mode).
__device__ __forceinline__ void mm_core(const f16* __restrict__ A, int lda,
                                        const f16* __restrict__ B, int ldb,
                                        int K, int m0, int n0,
                                        f16* As0, f16* Bs0, f16* As1, f16* Bs1,
                                        f32x4 (&acc)[4][4]) {
  const int tid  = threadIdx.x;
  const int lane = tid & 63;
  const int w    = tid >> 6;        // wave 0..3
  const int wm   = w >> 1, wn = w & 1;
  const int l15  = lane & 15;
  const int quad = lane >> 4;

  // staging pointers: wave w stages fragment-blocks bid = w*4 .. w*4+3 of A and B
  const f16* ag[4];
  const f16* bg[4];
  int lofs[4];
#pragma unroll
  for (int i = 0; i < 4; ++i) {
    const int bid = w * 4 + i;
    const int mt = bid >> 1;
    const int kt = bid & 1;
    ag[i] = A + (long)(m0 + mt * 16 + l15) * lda + kt * 32 + quad * 8;
    bg[i] = B + (long)(n0 + mt * 16 + l15) * ldb + kt * 32 + quad * 8;
    lofs[i] = bid * 512;
  }

  auto STAGE = [&](f16* Asb, f16* Bsb) {
#pragma unroll
    for (int i = 0; i < 4; ++i) {
      gload_lds16(ag[i], Asb + lofs[i]);
      gload_lds16(bg[i], Bsb + lofs[i]);
    }
#pragma unroll
    for (int i = 0; i < 4; ++i) { ag[i] += 64; bg[i] += 64; }
  };

  auto COMPUTE = [&](const f16* Ab, const f16* Bb) {
#pragma unroll
    for (int kt = 0; kt < 2; ++kt) {
      f16x8 af[4], bf[4];
#pragma unroll
      for (int i = 0; i < 4; ++i)
        af[i] = *(const f16x8*)(Ab + ((wm * 4 + i) * 2 + kt) * 512 + lane * 8);
#pragma unroll
      for (int j = 0; j < 4; ++j)
        bf[j] = *(const f16x8*)(Bb + ((wn * 4 + j) * 2 + kt) * 512 + lane * 8);
#pragma unroll
      for (int i = 0; i < 4; ++i)
#pragma unroll
        for (int j = 0; j < 4; ++j)
          acc[i][j] = __builtin_amdgcn_mfma_f32_16x16x32_f16(af[i], bf[j], acc[i][j], 0, 0, 0);
    }
  };

  // prologue: stage step 0 into buffer 0
  STAGE(As0, Bs0);
  __syncthreads();                  // step-0 tiles resident

  const int nt = K >> 6;            // even for all K used (16 or 32)
  for (int t = 0; t < nt; t += 2) {
    if (t + 1 < nt) STAGE(As1, Bs1);   // writes As1/Bs1 only
    COMPUTE(As0, Bs0);                 // reads As0/Bs0 only -> no vmcnt wait
    __syncthreads();                   // drain (hidden) + rw fence
    if (t + 2 < nt) STAGE(As0, Bs0);
    COMPUTE(As1, Bs1);
    __syncthreads();
  }
}

// ---------------------------------------------------------------------------
// Fused Q/K/V projection GEMM. grid = (8, 64, 3); z selects {A,W,bias,C,mode}.
// z=0: Q -> Qf (relu+bias, sin/cos dual write, ldc=2048)
// z=1: K -> Kn (same)
// z=2: V -> Vp (bias only, ldc=1024)
__launch_bounds__(256)
__global__ void proj_gemm(const f16* __restrict__ q16, const f16* __restrict__ k16,
                          const f16* __restrict__ v16, const f16* __restrict__ wq,
                          const f16* __restrict__ wk, const f16* __restrict__ wv,
                          const float* __restrict__ bq, const float* __restrict__ bk,
                          const float* __restrict__ bv,
                          f16* __restrict__ Qf, f16* __restrict__ Kn, f16* __restrict__ Vp) {
  __shared__ f16 As0[16 * 512];   // 4 x 16 KB, statically distinct buffers
  __shared__ f16 Bs0[16 * 512];
  __shared__ f16 As1[16 * 512];
  __shared__ f16 Bs1[16 * 512];
  int bx, by, z;
  xcd_swz(bx, by, z);
  const f16* A = (z == 0) ? q16 : (z == 1) ? k16 : v16;
  const f16* B = (z == 0) ? wq : (z == 1) ? wk : wv;
  const float* bias = (z == 0) ? bq : (z == 1) ? bk : bv;
  const int m0 = by * 128;
  const int n0 = bx * 128;

  f32x4 acc[4][4] = {};
  mm_core(A, 1024, B, 1024, 1024, m0, n0, As0, Bs0, As1, Bs1, acc);

  const int tid  = threadIdx.x;
  const int lane = tid & 63;
  const int w    = tid >> 6;
  const int wm   = w >> 1, wn = w & 1;
  const int l15  = lane & 15;
  const int quad = lane >> 4;

  // C/D layout (verified m89/m91): col = lane&15, row = quad*4 + reg.
  if (z < 2) {
    f16* C = (z == 0) ? Qf : Kn;
    const int ldc = 2048, halfw = 1024;
#pragma unroll
    for (int i = 0; i < 4; ++i) {
      const int mg = m0 + wm * 64 + i * 16 + quad * 4;
      float sn[4], cn[4];
#pragma unroll
      for (int rr = 0; rr < 4; ++rr) {
        const int l = (mg + rr) >> 2;          // natural row = l*4 + b
        const float ang = 7.6699039394282066e-4f * (float)(l + 1);  // (pi/2)/2048 * (l+1)
        __sincosf(ang, &sn[rr], &cn[rr]);
      }
#pragma unroll
      for (int j = 0; j < 4; ++j) {
        const int ng = n0 + wn * 64 + j * 16 + l15;
        const float bc = bias[ng];
#pragma unroll
        for (int rr = 0; rr < 4; ++rr) {
          const float v = fmaxf(acc[i][j][rr] + bc, 0.f);
          C[(long)(mg + rr) * ldc + ng]         = (f16)(v * sn[rr]);
          C[(long)(mg + rr) * ldc + ng + halfw] = (f16)(v * cn[rr]);
        }
      }
    }
  } else {
    f16* C = Vp;
    const int ldc = 1024;
#pragma unroll
    for (int i = 0; i < 4; ++i) {
      const int mg = m0 + wm * 64 + i * 16 + quad * 4;
#pragma unroll
      for (int j = 0; j < 4; ++j) {
        const int ng = n0 + wn * 64 + j * 16 + l15;
        const float bc = bias[ng];
#pragma unroll
        for (int rr = 0; rr < 4; ++rr)
          C[(long)(mg + rr) * ldc + ng] = (f16)(acc[i][j][rr] + bc);
      }
    }
  }
}

// ---------------------------------------------------------------------------
// Generic GEMM (kv and attn stages).
// MODE 2: kv   -> f16 C = acc
// MODE 3: attn -> f32 C = acc * z[l*4+bz]
template<int MODE>
__launch_bounds__(256)
__global__ void gemm_bt(const f16* __restrict__ A, int lda,
                        const f16* __restrict__ B, int ldb,
                        void* __restrict__ Cout, int K, int ldc,
                        const float* __restrict__ zvec,
                        long abatch, long bbatch, long cbatch)
{
  __shared__ f16 As0[16 * 512];   // 4 x 16 KB, statically distinct buffers
  __shared__ f16 Bs0[16 * 512];
  __shared__ f16 As1[16 * 512];
  __shared__ f16 Bs1[16 * 512];
  int bx, by, bz;
  xcd_swz(bx, by, bz);
  A += (long)bz * abatch;
  B += (long)bz * bbatch;
  const int m0 = by * 128;
  const int n0 = bx * 128;

  f32x4 acc[4][4] = {};
  mm_core(A, lda, B, ldb, K, m0, n0, As0, Bs0, As1, Bs1, acc);

  const int tid  = threadIdx.x;
  const int lane = tid & 63;
  const int w    = tid >> 6;
  const int wm   = w >> 1, wn = w & 1;
  const int l15  = lane & 15;
  const int quad = lane >> 4;

  if constexpr (MODE == 2) {
    f16* C = (f16*)Cout + (long)bz * cbatch;
#pragma unroll
    for (int i = 0; i < 4; ++i) {
      const int mg = m0 + wm * 64 + i * 16 + quad * 4;
#pragma unroll
      for (int j = 0; j < 4; ++j) {
        const int ng = n0 + wn * 64 + j * 16 + l15;
#pragma unroll
        for (int rr = 0; rr < 4; ++rr)
          C[(long)(mg + rr) * ldc + ng] = (f16)acc[i][j][rr];
      }
    }
  } else {  // MODE 3: attn, f32 out, scale by z
    float* C = (float*)Cout + (long)bz * cbatch;
#pragma unroll
    for (int i = 0; i < 4; ++i) {
      const int mg = m0 + wm * 64 + i * 16 + quad * 4;
      float zr[4];
#pragma unroll
      for (int rr = 0; rr < 4; ++rr) zr[rr] = zvec[(long)(mg + rr) * 4 + bz];
#pragma unroll
      for (int j = 0; j < 4; ++j) {
        const int ng = n0 + wn * 64 + j * 16 + l15;
#pragma unroll
        for (int rr = 0; rr < 4; ++rr)
          C[(long)(mg + rr) * ldc + ng] = acc[i][j][rr] * zr[rr];
      }
    }
  }
}

// ---------------------------------------------------------------------------
// fp16 64x64 LDS-tiled transpose, K and V fused in one launch.
// grid = (32, 32, 8): z<4 -> K batch z; z>=4 -> V batch z-4 (x<16 only).
__global__ void transpose_fused(const f16* __restrict__ Kn, f16* __restrict__ Kt,
                                const f16* __restrict__ Vp, f16* __restrict__ Vt) {
  __shared__ f16 tile[64 * 72];   // +8 halves pad (144B stride keeps 16B alignment)
  const int z = blockIdx.z;
  const f16* in;
  f16* out;
  long in_batch, out_batch;
  int ldin, ldout, b;
  if (z < 4) {
    in = Kn; out = Kt; in_batch = 2048; out_batch = 2048L * 2048;
    ldin = 8192; ldout = 2048; b = z;
  } else {
    if (blockIdx.x >= 16) return;   // V col dim is 1024 (uniform exit, pre-barrier)
    in = Vp; out = Vt; in_batch = 1024; out_batch = 1024L * 2048;
    ldin = 4096; ldout = 2048; b = z - 4;
  }
  in  += (long)b * in_batch;
  out += (long)b * out_batch;
  const int r0 = blockIdx.y * 64;
  const int c0 = blockIdx.x * 64;
  const int t  = threadIdx.x;
  {
    const int r = t >> 2, cs = (t & 3) * 16;
    const f16* src = in + (long)(r0 + r) * ldin + c0 + cs;
    f16x8 v0 = *(const f16x8*)(src);
    f16x8 v1 = *(const f16x8*)(src + 8);
    *(f16x8*)(tile + r * 72 + cs)     = v0;
    *(f16x8*)(tile + r * 72 + cs + 8) = v1;
  }
  __syncthreads();
  {
    const int c = t >> 2, rs = (t & 3) * 16;
    alignas(16) f16 tmp[16];
#pragma unroll
    for (int j = 0; j < 16; ++j) tmp[j] = tile[(rs + j) * 72 + c];
    f16* dst = out + (long)(c0 + c) * ldout + r0 + rs;
    *(f16x8*)(dst)     = *(const f16x8*)(tmp);
    *(f16x8*)(dst + 8) = *(const f16x8*)(tmp + 8);
  }
}

// ---------------------------------------------------------------------------
// k_sum[b][d] = sum_s K_t[b][d][s]  (one block per row of 2048)
__global__ void ksum_kernel(const f16* __restrict__ Kt, float* __restrict__ ks) {
  const long row = blockIdx.x;
  const int t = threadIdx.x;
  f16x8 v = *(const f16x8*)(Kt + row * 2048 + t * 8);
  float s = 0.f;
#pragma unroll
  for (int j = 0; j < 8; ++j) s += (float)v[j];
#pragma unroll
  for (int off = 32; off > 0; off >>= 1) s += __shfl_down(s, off, 64);
  __shared__ float red[4];
  if ((t & 63) == 0) red[t >> 6] = s;
  __syncthreads();
  if (t == 0) ks[row] = red[0] + red[1] + red[2] + red[3];
}

// z[r=l*4+b] = 1 / max(sum_d Q_[r][d] * k_sum[b][d], eps)
__global__ void z_kernel(const f16* __restrict__ Qf, const float* __restrict__ ks,
                         float* __restrict__ zb) {
  const long r = blockIdx.x;
  const int t = threadIdx.x;
  const int b = (int)(r & 3);
  f16x8 q = *(const f16x8*)(Qf + r * 2048 + t * 8);
  const float* kp = ks + b * 2048 + t * 8;
  float s = 0.f;
#pragma unroll
  for (int j = 0; j < 8; ++j) s += (float)q[j] * kp[j];
#pragma unroll
  for (int off = 32; off > 0; off >>= 1) s += __shfl_down(s, off, 64);
  __shared__ float red[4];
  if ((t & 63) == 0) red[t >> 6] = s;
  __syncthreads();
  if (t == 0) zb[r] = 1.f / fmaxf(red[0] + red[1] + red[2] + red[3], 1e-6f);
}

// ---------------------------------------------------------------------------
extern "C" void kernel_launch(void* const* d_in, const int* in_sizes, int n_in,
                              void* d_out, int out_size, void* d_ws, size_t ws_size,
                              hipStream_t stream) {
  const float* query = (const float*)d_in[0];
  const float* key_  = (const float*)d_in[1];
  const float* value = (const float*)d_in[2];
  const float* Wq    = (const float*)d_in[3];
  const float* bq    = (const float*)d_in[4];
  const float* Wk    = (const float*)d_in[5];
  const float* bk    = (const float*)d_in[6];
  const float* Wv    = (const float*)d_in[7];
  const float* bv    = (const float*)d_in[8];

  char* ws = (char*)d_ws;
  const size_t MB = 1ull << 20;
  // Workspace layout (peak 134 MB, with lifetime-based aliasing):
  f16* wq16 = (f16*)(ws + 0 * MB);    // 2 MB
  f16* wk16 = (f16*)(ws + 2 * MB);    // 2 MB
  f16* wv16 = (f16*)(ws + 4 * MB);    // 2 MB
  f16* q16  = (f16*)(ws + 6 * MB);    // 16 MB (dead after proj GEMMs)
  f16* k16  = (f16*)(ws + 22 * MB);   // 16 MB (dead after proj GEMMs)
  f16* v16  = (f16*)(ws + 38 * MB);   // 16 MB (dead after proj GEMMs)
  f16* Qf   = (f16*)(ws + 54 * MB);   // 32 MB  Q_ [l*4+b][2048]
  f16* Kn   = (f16*)(ws + 86 * MB);   // 32 MB  K_ natural [s*4+b][2048] (dead after transpose)
  f16* Vp   = (f16*)(ws + 118 * MB);  // 16 MB  V  natural [s*4+b][1024] (dead after transpose)
  f16* Kt   = (f16*)(ws + 6 * MB);    // 32 MB  K_t [b][d][s]   (aliases q16+k16)
  f16* Vt   = (f16*)(ws + 38 * MB);   // 16 MB  V_t [b][m][s]   (aliases v16)
  f16* kvb  = (f16*)(ws + 86 * MB);   // 16 MB  kv  [b][m][d]   (aliases Kn)
  float* ks = (float*)(ws + 102 * MB);  // 32 KB k_sum[b][d]
  float* zb = (float*)(ws + 103 * MB);  // 32 KB z[l*4+b]

  // 1) f32 -> f16 (2 fused launches)
  cvt3<<<dim3(8192, 1, 3), 256, 0, stream>>>(query, key_, value, q16, k16, v16, 2097152);
  cvt3<<<dim3(1024, 1, 3), 256, 0, stream>>>(Wq, Wk, Wv, wq16, wk16, wv16, 262144);

  // 2) projections fused (M=8192, N=1024, K=1024; z selects Q/K/V)
  proj_gemm<<<dim3(8, 64, 3), 256, 0, stream>>>(q16, k16, v16, wq16, wk16, wv16,
                                                bq, bk, bv, Qf, Kn, Vp);

  // 3) transposes fused: K_ [s][d] -> K_t [d][s]; V [s][m] -> V_t [m][s]
  transpose_fused<<<dim3(32, 32, 8), 256, 0, stream>>>(Kn, Kt, Vp, Vt);

  // 4) k_sum and z
  ksum_kernel<<<8192, 256, 0, stream>>>(Kt, ks);
  z_kernel<<<8192, 256, 0, stream>>>(Qf, ks, zb);

  // 5) kv[b][m][d] = sum_s V_t[m][s] * K_t[d][s]   (M=1024, N=2048, K=2048)
  gemm_bt<2><<<dim3(16, 8, 4), 256, 0, stream>>>(Vt, 2048, Kt, 2048, kvb, 2048, 2048,
                                                 nullptr, 1024L * 2048, 2048L * 2048, 1024L * 2048);
  // 6) attn[l][b][m] = z * sum_d Q_[l][d] * kv[m][d]  (M=2048, N=1024, K=2048), f32 out
  gemm_bt<3><<<dim3(8, 16, 4), 256, 0, stream>>>(Qf, 8192, kvb, 2048, d_out, 2048, 4096,
                                                 zb, 2048, 1024L * 2048, 1024);
}

// Round 7
// 372.671 us; speedup vs baseline: 1.1858x; 1.1280x over previous
//
#include <hip/hip_runtime.h>
#include <hip/hip_fp16.h>

// cosFormer linear attention, MI355X. L=S=2048, B=4, E=1024.
// Pipeline: f32->f16 convert; 3 proj GEMMs (fp16 MFMA, fp32 acc, epilogue folds
// bias/relu/sin-cos concat); LDS-tiled transposes; k_sum + z reductions;
// kv GEMM; attn GEMM (epilogue * z) -> f32 out.
// R1: fused launches (15 -> 8 dispatches).
// R2: XCD swizzle: FETCH 204->49 MB (ideal) but latency-bound, 115us.
// R3: runtime-offset dbuf REGRESSED (alias-conservative vmcnt(0) before ds_reads).
// R5: static dbuf NEUTRAL (118us): depth-1 prefetch + full-drain barrier can't
//     cover ~900cy HBM latency of the streamed A operand.
// R7: counted-vmcnt depth-2 pipeline (T3+T4): BM256xBN128, BK=32, 512 thr
//     (8 waves 4Mx2N, same verified 4x4 frag code), 4 static LDS buffer pairs
//     (96KB), prefetch depth 2. Per sub-step: vmcnt(3) BEFORE s_barrier (each
//     wave's own 3 stage-loads for the tile-to-compute retired; barrier makes
//     it cross-wave), sched_barrier(0) pins ds_reads below the barrier, then
//     STAGE(t+2) + COMPUTE(t). Epilogue waits 3/3/3/0. nt ≡ 0 mod 4 -> static
//     x4 buffer rotation. Grids: proj 768 blocks, kv/attn exactly 256 (1/CU).

typedef _Float16 f16;
typedef f16 f16x8 __attribute__((ext_vector_type(8)));
typedef f16 f16x4 __attribute__((ext_vector_type(4)));
typedef float f32x4 __attribute__((ext_vector_type(4)));

#define AS1 __attribute__((address_space(1)))
#define AS3 __attribute__((address_space(3)))

__device__ __forceinline__ void gload_lds16(const void* g, void* l) {
  // async global->LDS, 16B/lane; LDS dest = wave-uniform base + lane*16
  __builtin_amdgcn_global_load_lds((const AS1 void*)g, (AS3 void*)l, 16, 0, 0);
}

// XCD-chunked bijective swizzle (T1). Requires nwg % 8 == 0 (all our grids).
__device__ __forceinline__ void xcd_swz(int& bx, int& by, int& bz) {
  const int nx = gridDim.x, ny = gridDim.y;
  const int p = blockIdx.x + nx * (blockIdx.y + ny * blockIdx.z);
  const int chunk = (nx * ny * gridDim.z) >> 3;
  const int l = (p & 7) * chunk + (p >> 3);
  bx = l % nx;
  by = (l / nx) % ny;
  bz = l / (nx * ny);
}

// ---------------------------------------------------------------------------
// f32 -> f16 convert (vectorized x4); z selects one of three src/dst pairs
__global__ void cvt3(const float* __restrict__ s0, const float* __restrict__ s1,
                     const float* __restrict__ s2, f16* __restrict__ d0,
                     f16* __restrict__ d1, f16* __restrict__ d2, int n4) {
  const int z = blockIdx.z;
  const float* s = (z == 0) ? s0 : (z == 1) ? s1 : s2;
  f16* d = (z == 0) ? d0 : (z == 1) ? d1 : d2;
  const int i = blockIdx.x * 256 + threadIdx.x;
  if (i >= n4) return;
  const float4 v = ((const float4*)s)[i];
  f16x4 o = { (f16)v.x, (f16)v.y, (f16)v.z, (f16)v.w };
  ((f16x4*)d)[i] = o;
}

// ---------------------------------------------------------------------------
// Depth-2 counted-vmcnt pipelined 256x128x(BK=32) fp16 MFMA core.
//   acc[m][n] += sum_k A[m][k] * B[n][k]   (both operands k-contiguous)
// LDS per buffer: A = 16 blocks, B = 8 blocks of 1KB (16 rows x 32 k);
// block mt: lane l's 16B = row mt*16+(l&15), k quad*8..+7 -> ds_read_b128 at
// blockbase + lane*16 is conflict-free (counter-verified 0 on this layout).
// 8 waves: wave w stages A blocks {w, 8+w} and B block {w} (3 gloads/stage).
// Steady state: 2 stages (6 loads) in flight; vmcnt(3) retires the oldest
// stage; barrier makes that cross-wave; sched_barrier(0) keeps ds_reads below.
__device__ __forceinline__ void mm_core(const f16* __restrict__ A, int lda,
                                        const f16* __restrict__ B, int ldb,
                                        int K, int m0, int n0,
                                        f16* As0, f16* Bs0, f16* As1, f16* Bs1,
                                        f16* As2, f16* Bs2, f16* As3, f16* Bs3,
                                        f32x4 (&acc)[4][4]) {
  const int tid  = threadIdx.x;
  const int lane = tid & 63;
  const int w    = tid >> 6;        // wave 0..7
  const int wm   = w >> 1, wn = w & 1;
  const int l15  = lane & 15;
  const int quad = lane >> 4;

  const f16* pa0 = A + (long)(m0 + w * 16 + l15) * lda + quad * 8;        // A block w
  const f16* pa1 = A + (long)(m0 + (8 + w) * 16 + l15) * lda + quad * 8;  // A block 8+w
  const f16* pb0 = B + (long)(n0 + w * 16 + l15) * ldb + quad * 8;        // B block w
  int koff = 0;

#define STAGE_(Ab, Bb) do {                        \
    gload_lds16(pa0 + koff, (Ab) + w * 512);       \
    gload_lds16(pa1 + koff, (Ab) + (8 + w) * 512); \
    gload_lds16(pb0 + koff, (Bb) + w * 512);       \
    koff += 32; } while (0)

#define COMPUTE_(Ab, Bb) do {                                                    \
    f16x8 af[4], bf[4];                                                          \
    _Pragma("unroll")                                                            \
    for (int i = 0; i < 4; ++i)                                                  \
      af[i] = *(const f16x8*)((Ab) + (wm * 4 + i) * 512 + lane * 8);             \
    _Pragma("unroll")                                                            \
    for (int j = 0; j < 4; ++j)                                                  \
      bf[j] = *(const f16x8*)((Bb) + (wn * 4 + j) * 512 + lane * 8);             \
    _Pragma("unroll")                                                            \
    for (int i = 0; i < 4; ++i)                                                  \
      _Pragma("unroll")                                                          \
      for (int j = 0; j < 4; ++j)                                                \
        acc[i][j] = __builtin_amdgcn_mfma_f32_16x16x32_f16(af[i], bf[j],         \
                                                           acc[i][j], 0, 0, 0); \
  } while (0)

#define WV3_ asm volatile("s_waitcnt vmcnt(3)" ::: "memory")
#define WV0_ asm volatile("s_waitcnt vmcnt(0)" ::: "memory")
#define BARR_ do { __builtin_amdgcn_s_barrier(); __builtin_amdgcn_sched_barrier(0); } while (0)

  // prologue: 2 stages in flight
  STAGE_(As0, Bs0);
  STAGE_(As1, Bs1);

  const int nt = K >> 5;            // 32 (K=1024) or 64 (K=2048); nt % 4 == 0
  for (int t = 0; t + 5 < nt; t += 4) {
    WV3_; BARR_; STAGE_(As2, Bs2); COMPUTE_(As0, Bs0);
    WV3_; BARR_; STAGE_(As3, Bs3); COMPUTE_(As1, Bs1);
    WV3_; BARR_; STAGE_(As0, Bs0); COMPUTE_(As2, Bs2);
    WV3_; BARR_; STAGE_(As1, Bs1); COMPUTE_(As3, Bs3);
  }
  // peeled final 4 sub-steps (t == nt-4): stages nt-2, nt-1 then drain
  WV3_; BARR_; STAGE_(As2, Bs2); COMPUTE_(As0, Bs0);
  WV3_; BARR_; STAGE_(As3, Bs3); COMPUTE_(As1, Bs1);
  WV3_; BARR_; COMPUTE_(As2, Bs2);   // 6 outstanding -> retires stage(nt-2)
  WV0_; BARR_; COMPUTE_(As3, Bs3);   // 3 outstanding -> full drain

#undef STAGE_
#undef COMPUTE_
#undef WV3_
#undef WV0_
#undef BARR_
}

#define GEMM_LDS                                   \
  __shared__ alignas(16) f16 As0[8192];            \
  __shared__ alignas(16) f16 Bs0[4096];            \
  __shared__ alignas(16) f16 As1[8192];            \
  __shared__ alignas(16) f16 Bs1[4096];            \
  __shared__ alignas(16) f16 As2[8192];            \
  __shared__ alignas(16) f16 Bs2[4096];            \
  __shared__ alignas(16) f16 As3[8192];            \
  __shared__ alignas(16) f16 Bs3[4096];

// ---------------------------------------------------------------------------
// Fused Q/K/V projection GEMM. grid = (8, 32, 3), 512 thr; z selects set.
// z=0: Q -> Qf (relu+bias, sin/cos dual write, ldc=2048)
// z=1: K -> Kn (same)
// z=2: V -> Vp (bias only, ldc=1024)
__launch_bounds__(512, 2)
__global__ void proj_gemm(const f16* __restrict__ q16, const f16* __restrict__ k16,
                          const f16* __restrict__ v16, const f16* __restrict__ wq,
                          const f16* __restrict__ wk, const f16* __restrict__ wv,
                          const float* __restrict__ bq, const float* __restrict__ bk,
                          const float* __restrict__ bv,
                          f16* __restrict__ Qf, f16* __restrict__ Kn, f16* __restrict__ Vp) {
  GEMM_LDS
  int bx, by, z;
  xcd_swz(bx, by, z);
  const f16* A = (z == 0) ? q16 : (z == 1) ? k16 : v16;
  const f16* B = (z == 0) ? wq : (z == 1) ? wk : wv;
  const float* bias = (z == 0) ? bq : (z == 1) ? bk : bv;
  const int m0 = by * 256;
  const int n0 = bx * 128;

  f32x4 acc[4][4] = {};
  mm_core(A, 1024, B, 1024, 1024, m0, n0,
          As0, Bs0, As1, Bs1, As2, Bs2, As3, Bs3, acc);

  const int tid  = threadIdx.x;
  const int lane = tid & 63;
  const int w    = tid >> 6;
  const int wm   = w >> 1, wn = w & 1;
  const int l15  = lane & 15;
  const int quad = lane >> 4;

  // C/D layout (verified m89/m91): col = lane&15, row = quad*4 + reg.
  if (z < 2) {
    f16* C = (z == 0) ? Qf : Kn;
    const int ldc = 2048, halfw = 1024;
#pragma unroll
    for (int i = 0; i < 4; ++i) {
      const int mg = m0 + wm * 64 + i * 16 + quad * 4;
      float sn[4], cn[4];
#pragma unroll
      for (int rr = 0; rr < 4; ++rr) {
        const int l = (mg + rr) >> 2;          // natural row = l*4 + b
        const float ang = 7.6699039394282066e-4f * (float)(l + 1);  // (pi/2)/2048 * (l+1)
        __sincosf(ang, &sn[rr], &cn[rr]);
      }
#pragma unroll
      for (int j = 0; j < 4; ++j) {
        const int ng = n0 + wn * 64 + j * 16 + l15;
        const float bc = bias[ng];
#pragma unroll
        for (int rr = 0; rr < 4; ++rr) {
          const float v = fmaxf(acc[i][j][rr] + bc, 0.f);
          C[(long)(mg + rr) * ldc + ng]         = (f16)(v * sn[rr]);
          C[(long)(mg + rr) * ldc + ng + halfw] = (f16)(v * cn[rr]);
        }
      }
    }
  } else {
    f16* C = Vp;
    const int ldc = 1024;
#pragma unroll
    for (int i = 0; i < 4; ++i) {
      const int mg = m0 + wm * 64 + i * 16 + quad * 4;
#pragma unroll
      for (int j = 0; j < 4; ++j) {
        const int ng = n0 + wn * 64 + j * 16 + l15;
        const float bc = bias[ng];
#pragma unroll
        for (int rr = 0; rr < 4; ++rr)
          C[(long)(mg + rr) * ldc + ng] = (f16)(acc[i][j][rr] + bc);
      }
    }
  }
}

// ---------------------------------------------------------------------------
// Generic GEMM (kv and attn stages), 512 thr, BM=256/BN=128.
// MODE 2: kv   -> f16 C = acc
// MODE 3: attn -> f32 C = acc * z[l*4+bz]
template<int MODE>
__launch_bounds__(512, 2)
__global__ void gemm_bt(const f16* __restrict__ A, int lda,
                        const f16* __restrict__ B, int ldb,
                        void* __restrict__ Cout, int K, int ldc,
                        const float* __restrict__ zvec,
                        long abatch, long bbatch, long cbatch)
{
  GEMM_LDS
  int bx, by, bz;
  xcd_swz(bx, by, bz);
  A += (long)bz * abatch;
  B += (long)bz * bbatch;
  const int m0 = by * 256;
  const int n0 = bx * 128;

  f32x4 acc[4][4] = {};
  mm_core(A, lda, B, ldb, K, m0, n0,
          As0, Bs0, As1, Bs1, As2, Bs2, As3, Bs3, acc);

  const int tid  = threadIdx.x;
  const int lane = tid & 63;
  const int w    = tid >> 6;
  const int wm   = w >> 1, wn = w & 1;
  const int l15  = lane & 15;
  const int quad = lane >> 4;

  if constexpr (MODE == 2) {
    f16* C = (f16*)Cout + (long)bz * cbatch;
#pragma unroll
    for (int i = 0; i < 4; ++i) {
      const int mg = m0 + wm * 64 + i * 16 + quad * 4;
#pragma unroll
      for (int j = 0; j < 4; ++j) {
        const int ng = n0 + wn * 64 + j * 16 + l15;
#pragma unroll
        for (int rr = 0; rr < 4; ++rr)
          C[(long)(mg + rr) * ldc + ng] = (f16)acc[i][j][rr];
      }
    }
  } else {  // MODE 3: attn, f32 out, scale by z
    float* C = (float*)Cout + (long)bz * cbatch;
#pragma unroll
    for (int i = 0; i < 4; ++i) {
      const int mg = m0 + wm * 64 + i * 16 + quad * 4;
      float zr[4];
#pragma unroll
      for (int rr = 0; rr < 4; ++rr) zr[rr] = zvec[(long)(mg + rr) * 4 + bz];
#pragma unroll
      for (int j = 0; j < 4; ++j) {
        const int ng = n0 + wn * 64 + j * 16 + l15;
#pragma unroll
        for (int rr = 0; rr < 4; ++rr)
          C[(long)(mg + rr) * ldc + ng] = acc[i][j][rr] * zr[rr];
      }
    }
  }
}

// ---------------------------------------------------------------------------
// fp16 64x64 LDS-tiled transpose, K and V fused in one launch.
// grid = (32, 32, 8): z<4 -> K batch z; z>=4 -> V batch z-4 (x<16 only).
__global__ void transpose_fused(const f16* __restrict__ Kn, f16* __restrict__ Kt,
                                const f16* __restrict__ Vp, f16* __restrict__ Vt) {
  __shared__ f16 tile[64 * 72];   // +8 halves pad (144B stride keeps 16B alignment)
  const int z = blockIdx.z;
  const f16* in;
  f16* out;
  long in_batch, out_batch;
  int ldin, ldout, b;
  if (z < 4) {
    in = Kn; out = Kt; in_batch = 2048; out_batch = 2048L * 2048;
    ldin = 8192; ldout = 2048; b = z;
  } else {
    if (blockIdx.x >= 16) return;   // V col dim is 1024 (uniform exit, pre-barrier)
    in = Vp; out = Vt; in_batch = 1024; out_batch = 1024L * 2048;
    ldin = 4096; ldout = 2048; b = z - 4;
  }
  in  += (long)b * in_batch;
  out += (long)b * out_batch;
  const int r0 = blockIdx.y * 64;
  const int c0 = blockIdx.x * 64;
  const int t  = threadIdx.x;
  {
    const int r = t >> 2, cs = (t & 3) * 16;
    const f16* src = in + (long)(r0 + r) * ldin + c0 + cs;
    f16x8 v0 = *(const f16x8*)(src);
    f16x8 v1 = *(const f16x8*)(src + 8);
    *(f16x8*)(tile + r * 72 + cs)     = v0;
    *(f16x8*)(tile + r * 72 + cs + 8) = v1;
  }
  __syncthreads();
  {
    const int c = t >> 2, rs = (t & 3) * 16;
    alignas(16) f16 tmp[16];
#pragma unroll
    for (int j = 0; j < 16; ++j) tmp[j] = tile[(rs + j) * 72 + c];
    f16* dst = out + (long)(c0 + c) * ldout + r0 + rs;
    *(f16x8*)(dst)     = *(const f16x8*)(tmp);
    *(f16x8*)(dst + 8) = *(const f16x8*)(tmp + 8);
  }
}

// ---------------------------------------------------------------------------
// k_sum[b][d] = sum_s K_t[b][d][s]  (one block per row of 2048)
__global__ void ksum_kernel(const f16* __restrict__ Kt, float* __restrict__ ks) {
  const long row = blockIdx.x;
  const int t = threadIdx.x;
  f16x8 v = *(const f16x8*)(Kt + row * 2048 + t * 8);
  float s = 0.f;
#pragma unroll
  for (int j = 0; j < 8; ++j) s += (float)v[j];
#pragma unroll
  for (int off = 32; off > 0; off >>= 1) s += __shfl_down(s, off, 64);
  __shared__ float red[4];
  if ((t & 63) == 0) red[t >> 6] = s;
  __syncthreads();
  if (t == 0) ks[row] = red[0] + red[1] + red[2] + red[3];
}

// z[r=l*4+b] = 1 / max(sum_d Q_[r][d] * k_sum[b][d], eps)
__global__ void z_kernel(const f16* __restrict__ Qf, const float* __restrict__ ks,
                         float* __restrict__ zb) {
  const long r = blockIdx.x;
  const int t = threadIdx.x;
  const int b = (int)(r & 3);
  f16x8 q = *(const f16x8*)(Qf + r * 2048 + t * 8);
  const float* kp = ks + b * 2048 + t * 8;
  float s = 0.f;
#pragma unroll
  for (int j = 0; j < 8; ++j) s += (float)q[j] * kp[j];
#pragma unroll
  for (int off = 32; off > 0; off >>= 1) s += __shfl_down(s, off, 64);
  __shared__ float red[4];
  if ((t & 63) == 0) red[t >> 6] = s;
  __syncthreads();
  if (t == 0) zb[r] = 1.f / fmaxf(red[0] + red[1] + red[2] + red[3], 1e-6f);
}

// ---------------------------------------------------------------------------
extern "C" void kernel_launch(void* const* d_in, const int* in_sizes, int n_in,
                              void* d_out, int out_size, void* d_ws, size_t ws_size,
                              hipStream_t stream) {
  const float* query = (const float*)d_in[0];
  const float* key_  = (const float*)d_in[1];
  const float* value = (const float*)d_in[2];
  const float* Wq    = (const float*)d_in[3];
  const float* bq    = (const float*)d_in[4];
  const float* Wk    = (const float*)d_in[5];
  const float* bk    = (const float*)d_in[6];
  const float* Wv    = (const float*)d_in[7];
  const float* bv    = (const float*)d_in[8];

  char* ws = (char*)d_ws;
  const size_t MB = 1ull << 20;
  // Workspace layout (peak 134 MB, with lifetime-based aliasing):
  f16* wq16 = (f16*)(ws + 0 * MB);    // 2 MB
  f16* wk16 = (f16*)(ws + 2 * MB);    // 2 MB
  f16* wv16 = (f16*)(ws + 4 * MB);    // 2 MB
  f16* q16  = (f16*)(ws + 6 * MB);    // 16 MB (dead after proj GEMMs)
  f16* k16  = (f16*)(ws + 22 * MB);   // 16 MB (dead after proj GEMMs)
  f16* v16  = (f16*)(ws + 38 * MB);   // 16 MB (dead after proj GEMMs)
  f16* Qf   = (f16*)(ws + 54 * MB);   // 32 MB  Q_ [l*4+b][2048]
  f16* Kn   = (f16*)(ws + 86 * MB);   // 32 MB  K_ natural [s*4+b][2048] (dead after transpose)
  f16* Vp   = (f16*)(ws + 118 * MB);  // 16 MB  V  natural [s*4+b][1024] (dead after transpose)
  f16* Kt   = (f16*)(ws + 6 * MB);    // 32 MB  K_t [b][d][s]   (aliases q16+k16)
  f16* Vt   = (f16*)(ws + 38 * MB);   // 16 MB  V_t [b][m][s]   (aliases v16)
  f16* kvb  = (f16*)(ws + 86 * MB);   // 16 MB  kv  [b][m][d]   (aliases Kn)
  float* ks = (float*)(ws + 102 * MB);  // 32 KB k_sum[b][d]
  float* zb = (float*)(ws + 103 * MB);  // 32 KB z[l*4+b]

  // 1) f32 -> f16 (2 fused launches)
  cvt3<<<dim3(8192, 1, 3), 256, 0, stream>>>(query, key_, value, q16, k16, v16, 2097152);
  cvt3<<<dim3(1024, 1, 3), 256, 0, stream>>>(Wq, Wk, Wv, wq16, wk16, wv16, 262144);

  // 2) projections fused (M=8192, N=1024, K=1024; z selects Q/K/V); 768 blocks
  proj_gemm<<<dim3(8, 32, 3), 512, 0, stream>>>(q16, k16, v16, wq16, wk16, wv16,
                                                bq, bk, bv, Qf, Kn, Vp);

  // 3) transposes fused: K_ [s][d] -> K_t [d][s]; V [s][m] -> V_t [m][s]
  transpose_fused<<<dim3(32, 32, 8), 256, 0, stream>>>(Kn, Kt, Vp, Vt);

  // 4) k_sum and z
  ksum_kernel<<<8192, 256, 0, stream>>>(Kt, ks);
  z_kernel<<<8192, 256, 0, stream>>>(Qf, ks, zb);

  // 5) kv[b][m][d] = sum_s V_t[m][s] * K_t[d][s]  (M=1024, N=2048, K=2048); 256 blocks
  gemm_bt<2><<<dim3(16, 4, 4), 512, 0, stream>>>(Vt, 2048, Kt, 2048, kvb, 2048, 2048,
                                                 nullptr, 1024L * 2048, 2048L * 2048, 1024L * 2048);
  // 6) attn[l][b][m] = z * sum_d Q_[l][d] * kv[m][d]  (M=2048, N=1024, K=2048); 256 blocks
  gemm_bt<3><<<dim3(8, 8, 4), 512, 0, stream>>>(Qf, 8192, kvb, 2048, d_out, 2048, 4096,
                                                zb, 2048, 1024L * 2048, 1024);
}